// Round 2
// baseline (294.354 us; speedup 1.0000x reference)
//
#include <hip/hip_runtime.h>
#include <hip/hip_bf16.h>

#define NQ 8192
#define NG 2048
#define CTX 64
#define DQ 512
#define DK 256
#define DV 256
#define DZ 256

typedef __attribute__((ext_vector_type(8))) short short8;
typedef __attribute__((ext_vector_type(4))) float f32x4;

__device__ __forceinline__ unsigned short f2bf_bits(float f) {
  __hip_bfloat16 h = __float2bfloat16(f);
  return __builtin_bit_cast(unsigned short, h);
}
__device__ __forceinline__ float bf2f(unsigned short u) {
  unsigned int x = ((unsigned int)u) << 16;
  return __builtin_bit_cast(float, x);
}
__device__ __forceinline__ void split2(float x, unsigned short& h, unsigned short& l) {
  h = f2bf_bits(x);
  l = f2bf_bits(x - bf2f(h));
}
// load 8 consecutive f32, emit hi/lo bf16 split fragments
__device__ __forceinline__ void cvt8(const float* __restrict__ src, short8& h8, short8& l8) {
  f32x4 f0 = *reinterpret_cast<const f32x4*>(src);
  f32x4 f1 = *reinterpret_cast<const f32x4*>(src + 4);
#pragma unroll
  for (int j = 0; j < 4; j++) { unsigned short h, l; split2(f0[j], h, l); h8[j] = (short)h; l8[j] = (short)l; }
#pragma unroll
  for (int j = 0; j < 4; j++) { unsigned short h, l; split2(f1[j], h, l); h8[4 + j] = (short)h; l8[4 + j] = (short)l; }
}

// ---------------- prep: split+transpose weights, group ranges ----------------
__global__ void prep_kernel(const float* __restrict__ Wq, const float* __restrict__ Wk,
                            const int* __restrict__ gidx,
                            unsigned short* __restrict__ WqTh, unsigned short* __restrict__ WqTl,
                            unsigned short* __restrict__ WkTh, unsigned short* __restrict__ WkTl,
                            int* __restrict__ starts)
{
  int t = blockIdx.x * 256 + threadIdx.x;
  if (t < DZ * DQ) {                       // WqT*[z][kq] = Wq[kq][z]
    int z = t >> 9, kq = t & 511;
    unsigned short h, l; split2(Wq[(size_t)kq * DZ + z], h, l);
    WqTh[t] = h; WqTl[t] = l;
  } else if (t < DZ * DQ + DZ * DK) {      // WkT*[z][kx] = Wk[kx][z]
    int u = t - DZ * DQ;
    int z = u >> 8, kx = u & 255;
    unsigned short h, l; split2(Wk[(size_t)kx * DZ + z], h, l);
    WkTh[u] = h; WkTl[u] = l;
  } else if (t < DZ * DQ + DZ * DK + NG + 1) {
    int g = t - (DZ * DQ + DZ * DK);
    int lo = 0, hi = NQ;
    while (lo < hi) { int mid = (lo + hi) >> 1; if (gidx[mid] < g) lo = mid + 1; else hi = mid; }
    starts[g] = lo;
  }
}

// ---------------- mask dtype scan: flag=1 iff mask is 1-byte elements ----------------
__global__ void maskscan_kernel(const unsigned int* __restrict__ mw, int* __restrict__ flag)
{
  __shared__ int s[256];
  int t = threadIdx.x;
  int local = 0;
  for (int i = t; i < 32768; i += 256) {       // 32768 words always in-bounds (bool case = whole array)
    unsigned int w = mw[i];
    if (w != 0u && w != 1u && w != 0x3F800000u) local = 1;
  }
  s[t] = local;
  __syncthreads();
  for (int o = 128; o > 0; o >>= 1) { if (t < o) s[t] |= s[t + o]; __syncthreads(); }
  if (t == 0) flag[0] = s[0];
}

// ---------------- qz = (q @ Wq + bq) * 1/16, stored as split bf16 pair ----------------
__global__ __launch_bounds__(256) void qz_kernel(
    const float* __restrict__ q, const float* __restrict__ bq,
    const unsigned short* __restrict__ WqTh, const unsigned short* __restrict__ WqTl,
    unsigned short* __restrict__ qzh, unsigned short* __restrict__ qzl)
{
  const int tid = threadIdx.x;
  const int wave = tid >> 6, lane = tid & 63;
  const int i16 = lane & 15, hi4 = lane >> 4;
  const int mbase = blockIdx.x * 64;

  f32x4 acc[4][4];
#pragma unroll
  for (int a = 0; a < 4; a++)
#pragma unroll
    for (int b = 0; b < 4; b++) acc[a][b] = {0.f, 0.f, 0.f, 0.f};

  for (int kk = 0; kk < DQ; kk += 32) {
    short8 ah[4], al[4];
#pragma unroll
    for (int mt = 0; mt < 4; mt++)
      cvt8(q + (size_t)(mbase + mt * 16 + i16) * DQ + kk + hi4 * 8, ah[mt], al[mt]);
    short8 bh[4], bl[4];
#pragma unroll
    for (int nt = 0; nt < 4; nt++) {
      const int n = wave * 64 + nt * 16 + i16;
      bh[nt] = *reinterpret_cast<const short8*>(WqTh + (size_t)n * DQ + kk + hi4 * 8);
      bl[nt] = *reinterpret_cast<const short8*>(WqTl + (size_t)n * DQ + kk + hi4 * 8);
    }
#pragma unroll
    for (int mt = 0; mt < 4; mt++)
#pragma unroll
      for (int nt = 0; nt < 4; nt++) {
        acc[mt][nt] = __builtin_amdgcn_mfma_f32_16x16x32_bf16(ah[mt], bh[nt], acc[mt][nt], 0, 0, 0);
        acc[mt][nt] = __builtin_amdgcn_mfma_f32_16x16x32_bf16(al[mt], bh[nt], acc[mt][nt], 0, 0, 0);
        acc[mt][nt] = __builtin_amdgcn_mfma_f32_16x16x32_bf16(ah[mt], bl[nt], acc[mt][nt], 0, 0, 0);
      }
  }

  const float scale = 0.0625f;  // 1/sqrt(DZ) folded into qz
#pragma unroll
  for (int nt = 0; nt < 4; nt++) {
    const int n = wave * 64 + nt * 16 + i16;
    const float bias = bq[n];
#pragma unroll
    for (int mt = 0; mt < 4; mt++)
#pragma unroll
      for (int r = 0; r < 4; r++) {
        const int m = mbase + mt * 16 + hi4 * 4 + r;
        float x = (acc[mt][nt][r] + bias) * scale;
        unsigned short h, l; split2(x, h, l);
        qzh[(size_t)m * DZ + n] = h;
        qzl[(size_t)m * DZ + n] = l;
      }
  }
}

// ---------------- fused per-group: kz = k[g]@Wk+bk, masked softmax, PV ----------------
__global__ __launch_bounds__(256) void attn_kernel(
    const float* __restrict__ kmat, const float* __restrict__ vmat,
    const void* __restrict__ mmask, const int* __restrict__ mflagp,
    const int* __restrict__ starts, const float* __restrict__ bk,
    const unsigned short* __restrict__ WkTh, const unsigned short* __restrict__ WkTl,
    const unsigned short* __restrict__ qzh, const unsigned short* __restrict__ qzl,
    float* __restrict__ out)
{
  const int g = blockIdx.x;
  const int q0 = starts[g];
  const int q1 = starts[g + 1];
  if (q0 >= q1) return;

  const int tid = threadIdx.x;
  const int wave = tid >> 6, lane = tid & 63;
  const int i16 = lane & 15, hi4 = lane >> 4;

  __shared__ __align__(16) unsigned short kz_lds[CTX * DZ];       // 32 KB, XOR-swizzled rows
  __shared__ __align__(16) unsigned short ph_lds[4][CTX * 16];    // 8 KB
  __shared__ __align__(16) unsigned short pl_lds[4][CTX * 16];    // 8 KB
  __shared__ float maskbias[CTX];

  if (tid < CTX) {
    bool valid;
    if (mflagp[0])
      valid = ((const unsigned char*)mmask)[(size_t)g * CTX + tid] != 0;
    else
      valid = ((const unsigned int*)mmask)[(size_t)g * CTX + tid] != 0u;
    maskbias[tid] = valid ? 0.0f : -1e30f;
  }

  // ---- phase 1: kz = k[g] @ Wk + bk  (64x256), 3-term split bf16
  const float* kg = kmat + (size_t)g * (CTX * DK);
  f32x4 acc[4][4];
#pragma unroll
  for (int a = 0; a < 4; a++)
#pragma unroll
    for (int b = 0; b < 4; b++) acc[a][b] = {0.f, 0.f, 0.f, 0.f};

  for (int kk = 0; kk < DK; kk += 32) {
    short8 ah[4], al[4];
#pragma unroll
    for (int mt = 0; mt < 4; mt++)
      cvt8(kg + (mt * 16 + i16) * DK + kk + hi4 * 8, ah[mt], al[mt]);
    short8 bh[4], bl[4];
#pragma unroll
    for (int nt = 0; nt < 4; nt++) {
      const int n = wave * 64 + nt * 16 + i16;
      bh[nt] = *reinterpret_cast<const short8*>(WkTh + (size_t)n * DK + kk + hi4 * 8);
      bl[nt] = *reinterpret_cast<const short8*>(WkTl + (size_t)n * DK + kk + hi4 * 8);
    }
#pragma unroll
    for (int mt = 0; mt < 4; mt++)
#pragma unroll
      for (int nt = 0; nt < 4; nt++) {
        acc[mt][nt] = __builtin_amdgcn_mfma_f32_16x16x32_bf16(ah[mt], bh[nt], acc[mt][nt], 0, 0, 0);
        acc[mt][nt] = __builtin_amdgcn_mfma_f32_16x16x32_bf16(al[mt], bh[nt], acc[mt][nt], 0, 0, 0);
        acc[mt][nt] = __builtin_amdgcn_mfma_f32_16x16x32_bf16(ah[mt], bl[nt], acc[mt][nt], 0, 0, 0);
      }
  }

#pragma unroll
  for (int nt = 0; nt < 4; nt++) {
    const int n = wave * 64 + nt * 16 + i16;
    const float bias = bk[n];
#pragma unroll
    for (int mt = 0; mt < 4; mt++)
#pragma unroll
      for (int r = 0; r < 4; r++) {
        const int mrow = mt * 16 + hi4 * 4 + r;
        const int boff = (mrow * 512 + n * 2) ^ ((mrow & 7) << 4);
        *reinterpret_cast<unsigned short*>(reinterpret_cast<char*>(kz_lds) + boff)
            = f2bf_bits(acc[mt][nt][r] + bias);
      }
  }
  __syncthreads();

  float mb[16];
#pragma unroll
  for (int mt = 0; mt < 4; mt++)
#pragma unroll
    for (int r = 0; r < 4; r++)
      mb[mt * 4 + r] = maskbias[mt * 16 + hi4 * 4 + r];

  const float* vg = vmat + (size_t)g * (CTX * DV);

  // ---- phase 2: per 16-query chunk
  for (int c0 = 0; c0 < (q1 - q0); c0 += 16) {
    const int qbase = q0 + c0;
    f32x4 accs[4];
#pragma unroll
    for (int mt = 0; mt < 4; mt++) accs[mt] = {0.f, 0.f, 0.f, 0.f};

    int qrow = qbase + i16; if (qrow > NQ - 1) qrow = NQ - 1;  // clamp (masked at store)
    const unsigned short* qh_p = qzh + (size_t)qrow * DZ;
    const unsigned short* ql_p = qzl + (size_t)qrow * DZ;
#pragma unroll
    for (int kk = 0; kk < DZ; kk += 32) {
      short8 bfh = *reinterpret_cast<const short8*>(qh_p + kk + hi4 * 8);
      short8 bfl = *reinterpret_cast<const short8*>(ql_p + kk + hi4 * 8);
#pragma unroll
      for (int mt = 0; mt < 4; mt++) {
        const int mrow = mt * 16 + i16;
        const int boff = (mrow * 512 + (kk + hi4 * 8) * 2) ^ ((mrow & 7) << 4);
        short8 afz = *reinterpret_cast<const short8*>(reinterpret_cast<const char*>(kz_lds) + boff);
        accs[mt] = __builtin_amdgcn_mfma_f32_16x16x32_bf16(afz, bfh, accs[mt], 0, 0, 0);
        accs[mt] = __builtin_amdgcn_mfma_f32_16x16x32_bf16(afz, bfl, accs[mt], 0, 0, 0);
      }
    }

    // mask + softmax over 64 ctx rows (per query column i16)
    float mx = -3.0e38f;
#pragma unroll
    for (int mt = 0; mt < 4; mt++)
#pragma unroll
      for (int r = 0; r < 4; r++) {
        float s = accs[mt][r] + mb[mt * 4 + r];
        accs[mt][r] = s;
        mx = fmaxf(mx, s);
      }
    mx = fmaxf(mx, __shfl_xor(mx, 16));
    mx = fmaxf(mx, __shfl_xor(mx, 32));
    float sum = 0.f;
#pragma unroll
    for (int mt = 0; mt < 4; mt++)
#pragma unroll
      for (int r = 0; r < 4; r++) {
        float p = __expf(accs[mt][r] - mx);
        accs[mt][r] = p;
        sum += p;
      }
    sum += __shfl_xor(sum, 16);
    sum += __shfl_xor(sum, 32);
    const float inv = 1.0f / sum;

#pragma unroll
    for (int mt = 0; mt < 4; mt++)
#pragma unroll
      for (int r = 0; r < 4; r++) {
        const int mrow = mt * 16 + hi4 * 4 + r;
        unsigned short h, l; split2(accs[mt][r] * inv, h, l);
        ph_lds[wave][mrow * 16 + i16] = h;
        pl_lds[wave][mrow * 16 + i16] = l;
      }

    // PV: out_chunk(16 x 256) = P (16x64) @ v[g] (64x256); waves split d
    f32x4 acco[4];
#pragma unroll
    for (int nt = 0; nt < 4; nt++) acco[nt] = {0.f, 0.f, 0.f, 0.f};
#pragma unroll
    for (int kt = 0; kt < 2; kt++) {
      short8 pah, pal;
#pragma unroll
      for (int j = 0; j < 8; j++) {
        pah[j] = (short)ph_lds[wave][(kt * 32 + hi4 * 8 + j) * 16 + i16];
        pal[j] = (short)pl_lds[wave][(kt * 32 + hi4 * 8 + j) * 16 + i16];
      }
#pragma unroll
      for (int nt = 0; nt < 4; nt++) {
        const int d = wave * 64 + nt * 16 + i16;
        const float* vcol = vg + (size_t)(kt * 32 + hi4 * 8) * DV + d;
        short8 vb;
#pragma unroll
        for (int j = 0; j < 8; j++)
          vb[j] = (short)f2bf_bits(vcol[(size_t)j * DV]);
        acco[nt] = __builtin_amdgcn_mfma_f32_16x16x32_bf16(pah, vb, acco[nt], 0, 0, 0);
        acco[nt] = __builtin_amdgcn_mfma_f32_16x16x32_bf16(pal, vb, acco[nt], 0, 0, 0);
      }
    }

#pragma unroll
    for (int nt = 0; nt < 4; nt++) {
      const int d = wave * 64 + nt * 16 + i16;
#pragma unroll
      for (int r = 0; r < 4; r++) {
        const int qrow2 = qbase + hi4 * 4 + r;
        if (qrow2 < q1)
          out[(size_t)qrow2 * DV + d] = acco[nt][r];
      }
    }
  }
}

extern "C" void kernel_launch(void* const* d_in, const int* in_sizes, int n_in,
                              void* d_out, int out_size, void* d_ws, size_t ws_size,
                              hipStream_t stream) {
  const float* q  = (const float*)d_in[0];
  const float* k  = (const float*)d_in[1];
  const float* v  = (const float*)d_in[2];
  const void*  m  = d_in[3];
  const int* gidx = (const int*)d_in[4];
  const float* Wq = (const float*)d_in[5];
  const float* bq = (const float*)d_in[6];
  const float* Wk = (const float*)d_in[7];
  const float* bk = (const float*)d_in[8];
  float* out = (float*)d_out;

  char* ws = (char*)d_ws;
  unsigned short* qzh  = (unsigned short*)(ws);                         // 4 MB
  unsigned short* qzl  = (unsigned short*)(ws + 4194304);               // 4 MB
  unsigned short* WqTh = (unsigned short*)(ws + 8388608);               // 256 KB
  unsigned short* WqTl = (unsigned short*)(ws + 8388608 + 262144);      // 256 KB
  unsigned short* WkTh = (unsigned short*)(ws + 8388608 + 524288);      // 128 KB
  unsigned short* WkTl = (unsigned short*)(ws + 8388608 + 524288 + 131072); // 128 KB
  int* starts          = (int*)(ws + 8388608 + 524288 + 262144);        // 2049*4
  int* mflag           = (int*)(ws + 8388608 + 524288 + 262144 + 8208); // 4 B

  hipLaunchKernelGGL(prep_kernel, dim3(777), dim3(256), 0, stream,
                     Wq, Wk, gidx, WqTh, WqTl, WkTh, WkTl, starts);
  hipLaunchKernelGGL(maskscan_kernel, dim3(1), dim3(256), 0, stream,
                     (const unsigned int*)m, mflag);
  hipLaunchKernelGGL(qz_kernel, dim3(NQ / 64), dim3(256), 0, stream,
                     q, bq, WqTh, WqTl, qzh, qzl);
  hipLaunchKernelGGL(attn_kernel, dim3(NG), dim3(256), 0, stream,
                     k, v, m, (const int*)mflag, starts, bk, WkTh, WkTl, qzh, qzl, out);
}

// Round 3
// 238.614 us; speedup vs baseline: 1.2336x; 1.2336x over previous
//
#include <hip/hip_runtime.h>
#include <hip/hip_bf16.h>

#define NQ 8192
#define NG 2048
#define CTX 64
#define DQ 512
#define DK 256
#define DV 256
#define DZ 256

typedef __attribute__((ext_vector_type(8))) short short8;
typedef __attribute__((ext_vector_type(4))) float f32x4;

__device__ __forceinline__ unsigned short f2bf_bits(float f) {
  __hip_bfloat16 h = __float2bfloat16(f);
  return __builtin_bit_cast(unsigned short, h);
}
__device__ __forceinline__ float bf2f(unsigned short u) {
  unsigned int x = ((unsigned int)u) << 16;
  return __builtin_bit_cast(float, x);
}
__device__ __forceinline__ void split2(float x, unsigned short& h, unsigned short& l) {
  h = f2bf_bits(x);
  l = f2bf_bits(x - bf2f(h));
}
// hi+lo split of 8 consecutive f32 (already in regs)
__device__ __forceinline__ void cvt8_hl(f32x4 f0, f32x4 f1, short8& h8, short8& l8) {
#pragma unroll
  for (int j = 0; j < 4; j++) { unsigned short h, l; split2(f0[j], h, l); h8[j] = (short)h; l8[j] = (short)l; }
#pragma unroll
  for (int j = 0; j < 4; j++) { unsigned short h, l; split2(f1[j], h, l); h8[4 + j] = (short)h; l8[4 + j] = (short)l; }
}
// hi-only convert of 8 consecutive f32
__device__ __forceinline__ short8 cvt8_h(f32x4 f0, f32x4 f1) {
  short8 h8;
#pragma unroll
  for (int j = 0; j < 4; j++) h8[j] = (short)f2bf_bits(f0[j]);
#pragma unroll
  for (int j = 0; j < 4; j++) h8[4 + j] = (short)f2bf_bits(f1[j]);
  return h8;
}

// ---------------- prep: split+transpose weights, group ranges, flag init ----------------
__global__ void prep_kernel(const float* __restrict__ Wq, const float* __restrict__ Wk,
                            const int* __restrict__ gidx,
                            unsigned short* __restrict__ WqTh, unsigned short* __restrict__ WqTl,
                            unsigned short* __restrict__ WkTh, unsigned short* __restrict__ WkTl,
                            int* __restrict__ starts, int* __restrict__ mflag)
{
  int t = blockIdx.x * 256 + threadIdx.x;
  if (t < DZ * DQ) {                       // WqT*[z][kq] = Wq[kq][z]
    int z = t >> 9, kq = t & 511;
    unsigned short h, l; split2(Wq[(size_t)kq * DZ + z], h, l);
    WqTh[t] = h; WqTl[t] = l;
  } else if (t < DZ * DQ + DZ * DK) {      // WkT*[z][kx] = Wk[kx][z]
    int u = t - DZ * DQ;
    int z = u >> 8, kx = u & 255;
    unsigned short h, l; split2(Wk[(size_t)kx * DZ + z], h, l);
    WkTh[u] = h; WkTl[u] = l;
  } else if (t < DZ * DQ + DZ * DK + NG + 1) {
    int g = t - (DZ * DQ + DZ * DK);
    int lo = 0, hi = NQ;
    while (lo < hi) { int mid = (lo + hi) >> 1; if (gidx[mid] < g) lo = mid + 1; else hi = mid; }
    starts[g] = lo;
  } else if (t == DZ * DQ + DZ * DK + NG + 1) {
    mflag[0] = 0;
  }
}

// ---------------- mask dtype scan: flag=1 iff mask is 1-byte elements ----------------
__global__ void maskscan_kernel(const unsigned int* __restrict__ mw, int* __restrict__ flag)
{
  int i = blockIdx.x * 256 + threadIdx.x;     // 128 blocks x 256 = 32768 words, always in-bounds
  unsigned int w = mw[i];
  bool bad = (w != 0u && w != 1u && w != 0x3F800000u);
  if (__any(bad) && ((threadIdx.x & 63) == 0))
    atomicOr(flag, 1);
}

// ---------------- qz = (q @ Wq + bq) * 1/16, stored as split bf16 pair ----------------
__global__ __launch_bounds__(256, 4) void qz_kernel(
    const float* __restrict__ q, const float* __restrict__ bq,
    const unsigned short* __restrict__ WqTh, const unsigned short* __restrict__ WqTl,
    unsigned short* __restrict__ qzh, unsigned short* __restrict__ qzl)
{
  const int tid = threadIdx.x;
  const int wave = tid >> 6, lane = tid & 63;
  const int i16 = lane & 15, hi4 = lane >> 4;
  const int mbase = blockIdx.x * 32;

  f32x4 acc[2][4];
#pragma unroll
  for (int a = 0; a < 2; a++)
#pragma unroll
    for (int b = 0; b < 4; b++) acc[a][b] = {0.f, 0.f, 0.f, 0.f};

  for (int kk = 0; kk < DQ; kk += 32) {
    f32x4 araw[2][2];
#pragma unroll
    for (int mt = 0; mt < 2; mt++) {
      const float* src = q + (size_t)(mbase + mt * 16 + i16) * DQ + kk + hi4 * 8;
      araw[mt][0] = *reinterpret_cast<const f32x4*>(src);
      araw[mt][1] = *reinterpret_cast<const f32x4*>(src + 4);
    }
    short8 ah[2], al[2];
#pragma unroll
    for (int mt = 0; mt < 2; mt++) cvt8_hl(araw[mt][0], araw[mt][1], ah[mt], al[mt]);

#pragma unroll
    for (int ntp = 0; ntp < 2; ntp++) {
      short8 bh[2], bl[2];
#pragma unroll
      for (int j = 0; j < 2; j++) {
        const int n = wave * 64 + (ntp * 2 + j) * 16 + i16;
        bh[j] = *reinterpret_cast<const short8*>(WqTh + (size_t)n * DQ + kk + hi4 * 8);
        bl[j] = *reinterpret_cast<const short8*>(WqTl + (size_t)n * DQ + kk + hi4 * 8);
      }
#pragma unroll
      for (int mt = 0; mt < 2; mt++)
#pragma unroll
        for (int j = 0; j < 2; j++) {
          f32x4 a = acc[mt][ntp * 2 + j];
          a = __builtin_amdgcn_mfma_f32_16x16x32_bf16(ah[mt], bh[j], a, 0, 0, 0);
          a = __builtin_amdgcn_mfma_f32_16x16x32_bf16(al[mt], bh[j], a, 0, 0, 0);
          a = __builtin_amdgcn_mfma_f32_16x16x32_bf16(ah[mt], bl[j], a, 0, 0, 0);
          acc[mt][ntp * 2 + j] = a;
        }
    }
  }

  const float scale = 0.0625f;  // 1/sqrt(DZ) folded into qz
#pragma unroll
  for (int nt = 0; nt < 4; nt++) {
    const int n = wave * 64 + nt * 16 + i16;
    const float bias = bq[n];
#pragma unroll
    for (int mt = 0; mt < 2; mt++)
#pragma unroll
      for (int r = 0; r < 4; r++) {
        const int m = mbase + mt * 16 + hi4 * 4 + r;
        float x = (acc[mt][nt][r] + bias) * scale;
        unsigned short h, l; split2(x, h, l);
        qzh[(size_t)m * DZ + n] = h;
        qzl[(size_t)m * DZ + n] = l;
      }
  }
}

// ---------------- fused per-group: kz = k[g]@Wk+bk, masked softmax, PV ----------------
__global__ __launch_bounds__(256, 4) void attn_kernel(
    const float* __restrict__ kmat, const float* __restrict__ vmat,
    const void* __restrict__ mmask, const int* __restrict__ mflagp,
    const int* __restrict__ starts, const float* __restrict__ bk,
    const unsigned short* __restrict__ WkTh, const unsigned short* __restrict__ WkTl,
    const unsigned short* __restrict__ qzh, const unsigned short* __restrict__ qzl,
    float* __restrict__ out)
{
  const int g = blockIdx.x;
  const int q0 = starts[g];
  const int q1 = starts[g + 1];
  if (q0 >= q1) return;

  const int tid = threadIdx.x;
  const int wave = tid >> 6, lane = tid & 63;
  const int i16 = lane & 15, hi4 = lane >> 4;

  __shared__ __align__(16) unsigned short kz_lds[CTX * DZ];  // 32 KB, XOR-swizzled rows
  __shared__ __align__(16) unsigned short ph_lds[CTX * 16];  // 2 KB (shared, all waves write identical)
  __shared__ __align__(16) unsigned short pl_lds[CTX * 16];  // 2 KB
  __shared__ float maskbias[CTX];

  if (tid < CTX) {
    bool valid;
    if (mflagp[0])
      valid = ((const unsigned char*)mmask)[(size_t)g * CTX + tid] != 0;
    else
      valid = ((const unsigned int*)mmask)[(size_t)g * CTX + tid] != 0u;
    maskbias[tid] = valid ? 0.0f : -1e30f;
  }

  // ---- phase 1: kz = k[g] @ Wk + bk  (64x256), 2-term split (kh*Wh + kh*Wl)
  const float* kg = kmat + (size_t)g * (CTX * DK);
  f32x4 acc[4][4];
#pragma unroll
  for (int a = 0; a < 4; a++)
#pragma unroll
    for (int b = 0; b < 4; b++) acc[a][b] = {0.f, 0.f, 0.f, 0.f};

  for (int kk = 0; kk < DK; kk += 32) {
    f32x4 araw[4][2];
#pragma unroll
    for (int mt = 0; mt < 4; mt++) {
      const float* src = kg + (mt * 16 + i16) * DK + kk + hi4 * 8;
      araw[mt][0] = *reinterpret_cast<const f32x4*>(src);
      araw[mt][1] = *reinterpret_cast<const f32x4*>(src + 4);
    }
    short8 ah[4];
#pragma unroll
    for (int mt = 0; mt < 4; mt++) ah[mt] = cvt8_h(araw[mt][0], araw[mt][1]);

#pragma unroll
    for (int ntp = 0; ntp < 2; ntp++) {
      short8 bh[2], bl[2];
#pragma unroll
      for (int j = 0; j < 2; j++) {
        const int n = wave * 64 + (ntp * 2 + j) * 16 + i16;
        bh[j] = *reinterpret_cast<const short8*>(WkTh + (size_t)n * DK + kk + hi4 * 8);
        bl[j] = *reinterpret_cast<const short8*>(WkTl + (size_t)n * DK + kk + hi4 * 8);
      }
#pragma unroll
      for (int mt = 0; mt < 4; mt++)
#pragma unroll
        for (int j = 0; j < 2; j++) {
          f32x4 a = acc[mt][ntp * 2 + j];
          a = __builtin_amdgcn_mfma_f32_16x16x32_bf16(ah[mt], bh[j], a, 0, 0, 0);
          a = __builtin_amdgcn_mfma_f32_16x16x32_bf16(ah[mt], bl[j], a, 0, 0, 0);
          acc[mt][ntp * 2 + j] = a;
        }
    }
  }

#pragma unroll
  for (int nt = 0; nt < 4; nt++) {
    const int n = wave * 64 + nt * 16 + i16;
    const float bias = bk[n];
#pragma unroll
    for (int mt = 0; mt < 4; mt++)
#pragma unroll
      for (int r = 0; r < 4; r++) {
        const int mrow = mt * 16 + hi4 * 4 + r;
        const int boff = (mrow * 512 + n * 2) ^ ((mrow & 7) << 4);
        *reinterpret_cast<unsigned short*>(reinterpret_cast<char*>(kz_lds) + boff)
            = f2bf_bits(acc[mt][nt][r] + bias);
      }
  }
  __syncthreads();

  float mb[16];
#pragma unroll
  for (int mt = 0; mt < 4; mt++)
#pragma unroll
    for (int r = 0; r < 4; r++)
      mb[mt * 4 + r] = maskbias[mt * 16 + hi4 * 4 + r];

  const float* vg = vmat + (size_t)g * (CTX * DV);
  const int nchunks = (q1 - q0 + 15) >> 4;

  // ---- phase 2: per 16-query chunk
  for (int c = 0; c < nchunks; c++) {
    const int qbase = q0 + c * 16;
    f32x4 accs[4];
#pragma unroll
    for (int mt = 0; mt < 4; mt++) accs[mt] = {0.f, 0.f, 0.f, 0.f};

    int qrow = qbase + i16; if (qrow > NQ - 1) qrow = NQ - 1;  // clamp (masked at store)
    const unsigned short* qh_p = qzh + (size_t)qrow * DZ;
    const unsigned short* ql_p = qzl + (size_t)qrow * DZ;
#pragma unroll
    for (int kk = 0; kk < DZ; kk += 32) {
      short8 bfh = *reinterpret_cast<const short8*>(qh_p + kk + hi4 * 8);
      short8 bfl = *reinterpret_cast<const short8*>(ql_p + kk + hi4 * 8);
#pragma unroll
      for (int mt = 0; mt < 4; mt++) {
        const int mrow = mt * 16 + i16;
        const int boff = (mrow * 512 + (kk + hi4 * 8) * 2) ^ ((mrow & 7) << 4);
        short8 afz = *reinterpret_cast<const short8*>(reinterpret_cast<const char*>(kz_lds) + boff);
        accs[mt] = __builtin_amdgcn_mfma_f32_16x16x32_bf16(afz, bfh, accs[mt], 0, 0, 0);
        accs[mt] = __builtin_amdgcn_mfma_f32_16x16x32_bf16(afz, bfl, accs[mt], 0, 0, 0);
      }
    }

    // mask + softmax over 64 ctx rows (per query column i16)
    float mx = -3.0e38f;
#pragma unroll
    for (int mt = 0; mt < 4; mt++)
#pragma unroll
      for (int r = 0; r < 4; r++) {
        float s = accs[mt][r] + mb[mt * 4 + r];
        accs[mt][r] = s;
        mx = fmaxf(mx, s);
      }
    mx = fmaxf(mx, __shfl_xor(mx, 16));
    mx = fmaxf(mx, __shfl_xor(mx, 32));
    float sum = 0.f;
#pragma unroll
    for (int mt = 0; mt < 4; mt++)
#pragma unroll
      for (int r = 0; r < 4; r++) {
        float p = __expf(accs[mt][r] - mx);
        accs[mt][r] = p;
        sum += p;
      }
    sum += __shfl_xor(sum, 16);
    sum += __shfl_xor(sum, 32);
    const float inv = 1.0f / sum;

    __syncthreads();  // all waves done reading p_lds of previous chunk
#pragma unroll
    for (int mt = 0; mt < 4; mt++)
#pragma unroll
      for (int r = 0; r < 4; r++) {
        const int mrow = mt * 16 + hi4 * 4 + r;
        unsigned short h, l; split2(accs[mt][r] * inv, h, l);
        ph_lds[mrow * 16 + i16] = h;   // every wave writes the identical full tile;
        pl_lds[mrow * 16 + i16] = l;   // each wave reads only its own writes below
      }

    // PV: out_chunk(16 x 256) = P (16x64) @ v[g] (64x256); waves split d
    f32x4 acco[4];
#pragma unroll
    for (int nt = 0; nt < 4; nt++) acco[nt] = {0.f, 0.f, 0.f, 0.f};
#pragma unroll
    for (int kt = 0; kt < 2; kt++) {
      short8 pah, pal;
#pragma unroll
      for (int j = 0; j < 8; j++) {
        pah[j] = (short)ph_lds[(kt * 32 + hi4 * 8 + j) * 16 + i16];
        pal[j] = (short)pl_lds[(kt * 32 + hi4 * 8 + j) * 16 + i16];
      }
#pragma unroll
      for (int nt = 0; nt < 4; nt++) {
        const int d = wave * 64 + nt * 16 + i16;
        const float* vcol = vg + (size_t)(kt * 32 + hi4 * 8) * DV + d;
        short8 vb;
#pragma unroll
        for (int j = 0; j < 8; j++)
          vb[j] = (short)f2bf_bits(vcol[(size_t)j * DV]);
        acco[nt] = __builtin_amdgcn_mfma_f32_16x16x32_bf16(pah, vb, acco[nt], 0, 0, 0);
        acco[nt] = __builtin_amdgcn_mfma_f32_16x16x32_bf16(pal, vb, acco[nt], 0, 0, 0);
      }
    }

#pragma unroll
    for (int nt = 0; nt < 4; nt++) {
      const int d = wave * 64 + nt * 16 + i16;
#pragma unroll
      for (int r = 0; r < 4; r++) {
        const int qrow2 = qbase + hi4 * 4 + r;
        if (qrow2 < q1)
          out[(size_t)qrow2 * DV + d] = acco[nt][r];
      }
    }
  }
}

extern "C" void kernel_launch(void* const* d_in, const int* in_sizes, int n_in,
                              void* d_out, int out_size, void* d_ws, size_t ws_size,
                              hipStream_t stream) {
  const float* q  = (const float*)d_in[0];
  const float* k  = (const float*)d_in[1];
  const float* v  = (const float*)d_in[2];
  const void*  m  = d_in[3];
  const int* gidx = (const int*)d_in[4];
  const float* Wq = (const float*)d_in[5];
  const float* bq = (const float*)d_in[6];
  const float* Wk = (const float*)d_in[7];
  const float* bk = (const float*)d_in[8];
  float* out = (float*)d_out;

  char* ws = (char*)d_ws;
  unsigned short* qzh  = (unsigned short*)(ws);                         // 4 MB
  unsigned short* qzl  = (unsigned short*)(ws + 4194304);               // 4 MB
  unsigned short* WqTh = (unsigned short*)(ws + 8388608);               // 256 KB
  unsigned short* WqTl = (unsigned short*)(ws + 8388608 + 262144);      // 256 KB
  unsigned short* WkTh = (unsigned short*)(ws + 8388608 + 524288);      // 128 KB
  unsigned short* WkTl = (unsigned short*)(ws + 8388608 + 524288 + 131072); // 128 KB
  int* starts          = (int*)(ws + 8388608 + 524288 + 262144);        // 2049*4
  int* mflag           = (int*)(ws + 8388608 + 524288 + 262144 + 8208); // 4 B

  hipLaunchKernelGGL(prep_kernel, dim3(777), dim3(256), 0, stream,
                     Wq, Wk, gidx, WqTh, WqTl, WkTh, WkTl, starts, mflag);
  hipLaunchKernelGGL(maskscan_kernel, dim3(128), dim3(256), 0, stream,
                     (const unsigned int*)m, mflag);
  hipLaunchKernelGGL(qz_kernel, dim3(NQ / 32), dim3(256), 0, stream,
                     q, bq, WqTh, WqTl, qzh, qzl);
  hipLaunchKernelGGL(attn_kernel, dim3(NG), dim3(256), 0, stream,
                     k, v, m, (const int*)mflag, starts, bk, WkTh, WkTl, qzh, qzl, out);
}